// Round 3
// baseline (180.687 us; speedup 1.0000x reference)
//
#include <hip/hip_runtime.h>
#include <cmath>

// Problem constants: B=32768, N=17, D=2, K=3, H=64 (bMLP hidden=128, out=12)
#define NBATCH 32768
#define NJOINT 17
#define OUT0_ELEMS (NBATCH * NJOINT * 15)          // out[B,N,3,5]
#define KJS_OFF    OUT0_ELEMS                      // k_js[B,N]
#define MASK_OFF   (KJS_OFF + NBATCH * NJOINT)     // mask[B,N,3]

typedef float v2f __attribute__((ext_vector_type(2)));

__device__ __forceinline__ v2f pkfma(v2f a, v2f b, v2f c) { return __builtin_elementwise_fma(a, b, c); }
__device__ __forceinline__ v2f pkmax(v2f a, v2f b)        { return __builtin_elementwise_max(a, b); }

__device__ __forceinline__ float sel3f(int i, float a, float b, float c) {
    return (i == 0) ? a : ((i == 1) ? b : c);
}

// Cold path: exact fp64 recompute of a 2->64->3 MLP (reads global weights).
// Taken only when fp32 logits have a near-tie (< 1e-4 rel) that could flip
// the discrete argmax / argsort decisions.
__device__ __noinline__ void mlp64_small(
    const float* __restrict__ W1a, const float* __restrict__ W1b,
    const float* __restrict__ b1,  const float* __restrict__ W2,
    const float* __restrict__ b2,
    double x0, double x1, double& l0, double& l1, double& l2)
{
    l0 = (double)b2[0]; l1 = (double)b2[1]; l2 = (double)b2[2];
    for (int h = 0; h < 64; ++h) {
        double hv = fma(x1, (double)W1b[h], fma(x0, (double)W1a[h], (double)b1[h]));
        hv = fmax(hv, 0.0);
        l0 = fma(hv, (double)W2[h * 3 + 0], l0);
        l1 = fma(hv, (double)W2[h * 3 + 1], l1);
        l2 = fma(hv, (double)W2[h * 3 + 2], l2);
    }
}

// Per-point epilogue: tie-checks + argmax/argsort + softmax + exp + writes.
__device__ __forceinline__ void finish_point(
    float x0f, float x1f,
    float kf0, float kf1, float kf2,
    float wf0, float wf1, float wf2,
    const v2f* acc,        // 6 pairs = 12 bMLP outputs (+ bb2 already added)
    int n, int p,
    const float* __restrict__ kW1, const float* __restrict__ kb1,
    const float* __restrict__ kW2, const float* __restrict__ kb2,
    const float* __restrict__ wW1, const float* __restrict__ wb1,
    const float* __restrict__ wW2, const float* __restrict__ wb2,
    float* __restrict__ out)
{
    // k argmax with fp64 fallback on near-tie
    double kl0 = (double)kf0, kl1 = (double)kf1, kl2 = (double)kf2;
    {
        const float d01 = fabsf(kf0 - kf1), d02 = fabsf(kf0 - kf2), d12 = fabsf(kf1 - kf2);
        const float sc = fmaxf(fmaxf(fabsf(kf0), fabsf(kf1)), fabsf(kf2));
        if (fminf(fminf(d01, d02), d12) < 1e-4f * fmaxf(sc, 1.0f))
            mlp64_small(kW1 + n * 128, kW1 + n * 128 + 64, kb1 + n * 64,
                        kW2 + n * 192, kb2 + n * 3,
                        (double)x0f, (double)x1f, kl0, kl1, kl2);
    }
    int kj = 0;
    {
        double m = kl0;
        if (kl1 > m) { m = kl1; kj = 1; }
        if (kl2 > m) { kj = 2; }
    }

    // w argsort with fp64 fallback on near-tie
    double wl0 = (double)wf0, wl1 = (double)wf1, wl2 = (double)wf2;
    {
        const float d01 = fabsf(wf0 - wf1), d02 = fabsf(wf0 - wf2), d12 = fabsf(wf1 - wf2);
        const float sc = fmaxf(fmaxf(fabsf(wf0), fabsf(wf1)), fabsf(wf2));
        if (fminf(fminf(d01, d02), d12) < 1e-4f * fmaxf(sc, 1.0f))
            mlp64_small(wW1 + n * 128, wW1 + n * 128 + 64, wb1 + n * 64,
                        wW2 + n * 192, wb2 + n * 3,
                        (double)x0f, (double)x1f, wl0, wl1, wl2);
    }
    int i0 = 0;
    {
        double m = wl0;
        if (wl1 > m) { m = wl1; i0 = 1; }
        if (wl2 > m) { i0 = 2; }
    }
    const int ia = (i0 == 0) ? 1 : 0;
    const int ib = (i0 == 2) ? 1 : 2;
    const double wa = ia ? wl1 : wl0;
    const double wb = (ib == 1) ? wl1 : wl2;
    const int i1 = (wb > wa) ? ib : ia;
    const int i2 = (wb > wa) ? ia : ib;

    const float mw = fmaxf(fmaxf(wf0, wf1), wf2);
    const float e0 = __expf(wf0 - mw);
    const float e1 = __expf(wf1 - mw);
    const float e2 = __expf(wf2 - mw);
    const float inv = 1.0f / (e0 + e1 + e2);
    const float p0 = e0 * inv, p1 = e1 * inv, p2 = e2 * inv;

    float af[12];
    #pragma unroll
    for (int c = 0; c < 6; ++c) { af[2 * c] = acc[c].x; af[2 * c + 1] = acc[c].y; }

    float r[15];
    r[0]  = p0; r[5] = p1; r[10] = p2;
    r[1]  = sel3f(i0, af[0], af[4], af[8]);
    r[2]  = sel3f(i0, af[1], af[5], af[9]);
    r[3]  = __expf(sel3f(i0, af[2], af[6], af[10]));
    r[4]  = __expf(sel3f(i0, af[3], af[7], af[11]));
    r[6]  = sel3f(i1, af[0], af[4], af[8]);
    r[7]  = sel3f(i1, af[1], af[5], af[9]);
    r[8]  = __expf(sel3f(i1, af[2], af[6], af[10]));
    r[9]  = __expf(sel3f(i1, af[3], af[7], af[11]));
    r[11] = sel3f(i2, af[0], af[4], af[8]);
    r[12] = sel3f(i2, af[1], af[5], af[9]);
    r[13] = __expf(sel3f(i2, af[2], af[6], af[10]));
    r[14] = __expf(sel3f(i2, af[3], af[7], af[11]));

    float* o = out + (size_t)p * 15;
    #pragma unroll
    for (int i = 0; i < 15; ++i) o[i] = r[i];

    out[KJS_OFF + p] = (float)(kj + 1);

    float* mk = out + MASK_OFF + (size_t)p * 3;
    mk[0] = 1.0f;
    mk[1] = (kj >= 1) ? 1.0f : 0.0f;
    mk[2] = (kj >= 2) ? 1.0f : 0.0f;
}

// LDS layout (floats):
//  [0,384)    kRec: 32 records x 12: {w1a0,w1a1, w1b0,w1b1, b10,b11,
//                                     w2[o0,e],w2[o0,o], w2[o1,e],w2[o1,o], w2[o2,e],w2[o2,o]}
//  [384,768)  wRec: same
//  [768,2816) bRec: 64 records x 32: {w1a0,w1a1, w1b0,w1b1, b10,b11, pad,pad,
//                                     W2row(2r)[0..11], W2row(2r+1)[0..11]}
// All records are 16B-aligned -> ds_read_b128 broadcast reads, zero conflicts.
__global__ __launch_bounds__(256) void mdn_fused(
    const float* __restrict__ pred_pts,
    const float* __restrict__ kW1, const float* __restrict__ kb1,
    const float* __restrict__ kW2, const float* __restrict__ kb2,
    const float* __restrict__ wW1, const float* __restrict__ wb1,
    const float* __restrict__ wW2, const float* __restrict__ wb2,
    const float* __restrict__ bW1, const float* __restrict__ bb1,
    const float* __restrict__ bW2, const float* __restrict__ bb2,
    float* __restrict__ out)
{
    __shared__ float4 ldsq[704];               // 2816 floats = 11264 B
    float* lds = (float*)ldsq;

    const int t = threadIdx.x;
    const int n = blockIdx.y;                  // wave-uniform joint

    // ------------------- stage + repack weights into LDS -------------------
    if (t < 64) {
        const int r = t & 31;
        const bool isK = t < 32;
        const float* W1 = (isK ? kW1 : wW1) + n * 128;
        const float* B1 = (isK ? kb1 : wb1) + n * 64;
        const float* W2 = (isK ? kW2 : wW2) + n * 192;
        float* dst = lds + (isK ? 0 : 384) + r * 12;
        dst[0] = W1[2 * r];      dst[1] = W1[2 * r + 1];
        dst[2] = W1[64 + 2 * r]; dst[3] = W1[64 + 2 * r + 1];
        dst[4] = B1[2 * r];      dst[5] = B1[2 * r + 1];
        dst[6]  = W2[6 * r + 0]; dst[7]  = W2[6 * r + 3];   // pre-shuffled:
        dst[8]  = W2[6 * r + 1]; dst[9]  = W2[6 * r + 4];   // {even-h, odd-h}
        dst[10] = W2[6 * r + 2]; dst[11] = W2[6 * r + 5];   // per output
    } else if (t < 128) {
        const int r = t - 64;
        const float* W1 = bW1 + n * 256;
        const float* B1 = bb1 + n * 128;
        const float* W2 = bW2 + n * 1536;
        float* dst = lds + 768 + r * 32;
        dst[0] = W1[2 * r];       dst[1] = W1[2 * r + 1];
        dst[2] = W1[128 + 2 * r]; dst[3] = W1[128 + 2 * r + 1];
        dst[4] = B1[2 * r];       dst[5] = B1[2 * r + 1];
        dst[6] = 0.0f; dst[7] = 0.0f;
        #pragma unroll
        for (int j = 0; j < 12; ++j) dst[8 + j]  = W2[(2 * r) * 12 + j];
        #pragma unroll
        for (int j = 0; j < 12; ++j) dst[20 + j] = W2[(2 * r + 1) * 12 + j];
    }
    __syncthreads();

    // ------------------- two points per thread -----------------------------
    const int bA = blockIdx.x * 512 + t;       // point A
    const int bB = bA + 256;                   // point B
    const int pA = bA * NJOINT + n;
    const int pB = bB * NJOINT + n;

    const float2 xA = *reinterpret_cast<const float2*>(pred_pts + 2 * pA);
    const float2 xB = *reinterpret_cast<const float2*>(pred_pts + 2 * pB);
    const v2f vx0A = {xA.x, xA.x}, vx1A = {xA.y, xA.y};
    const v2f vx0B = {xB.x, xB.x}, vx1B = {xB.y, xB.y};
    const v2f vz = {0.f, 0.f};

    // ---------------- kMLP + wMLP from LDS (shared reads, A&B) -------------
    v2f ka0A = vz, ka1A = vz, ka2A = vz, ka0B = vz, ka1B = vz, ka2B = vz;
    v2f wa0A = vz, wa1A = vz, wa2A = vz, wa0B = vz, wa1B = vz, wa2B = vz;
    #pragma unroll 4
    for (int r = 0; r < 32; ++r) {
        {
            const float4* rp = (const float4*)(lds + r * 12);
            const float4 q0 = rp[0], q1 = rp[1], q2 = rp[2];
            const v2f w1a = {q0.x, q0.y}, w1b = {q0.z, q0.w}, bb = {q1.x, q1.y};
            const v2f p0 = {q1.z, q1.w}, p1 = {q2.x, q2.y}, p2 = {q2.z, q2.w};
            const v2f hA = pkmax(pkfma(vx1A, w1b, pkfma(vx0A, w1a, bb)), vz);
            const v2f hB = pkmax(pkfma(vx1B, w1b, pkfma(vx0B, w1a, bb)), vz);
            ka0A = pkfma(hA, p0, ka0A); ka1A = pkfma(hA, p1, ka1A); ka2A = pkfma(hA, p2, ka2A);
            ka0B = pkfma(hB, p0, ka0B); ka1B = pkfma(hB, p1, ka1B); ka2B = pkfma(hB, p2, ka2B);
        }
        {
            const float4* rp = (const float4*)(lds + 384 + r * 12);
            const float4 q0 = rp[0], q1 = rp[1], q2 = rp[2];
            const v2f w1a = {q0.x, q0.y}, w1b = {q0.z, q0.w}, bb = {q1.x, q1.y};
            const v2f p0 = {q1.z, q1.w}, p1 = {q2.x, q2.y}, p2 = {q2.z, q2.w};
            const v2f hA = pkmax(pkfma(vx1A, w1b, pkfma(vx0A, w1a, bb)), vz);
            const v2f hB = pkmax(pkfma(vx1B, w1b, pkfma(vx0B, w1a, bb)), vz);
            wa0A = pkfma(hA, p0, wa0A); wa1A = pkfma(hA, p1, wa1A); wa2A = pkfma(hA, p2, wa2A);
            wa0B = pkfma(hB, p0, wa0B); wa1B = pkfma(hB, p1, wa1B); wa2B = pkfma(hB, p2, wa2B);
        }
    }
    const float kb20 = kb2[n * 3 + 0], kb21 = kb2[n * 3 + 1], kb22 = kb2[n * 3 + 2];
    const float wb20 = wb2[n * 3 + 0], wb21 = wb2[n * 3 + 1], wb22 = wb2[n * 3 + 2];
    const float kf0A = ka0A.x + ka0A.y + kb20, kf1A = ka1A.x + ka1A.y + kb21, kf2A = ka2A.x + ka2A.y + kb22;
    const float kf0B = ka0B.x + ka0B.y + kb20, kf1B = ka1B.x + ka1B.y + kb21, kf2B = ka2B.x + ka2B.y + kb22;
    const float wf0A = wa0A.x + wa0A.y + wb20, wf1A = wa1A.x + wa1A.y + wb21, wf2A = wa2A.x + wa2A.y + wb22;
    const float wf0B = wa0B.x + wa0B.y + wb20, wf1B = wa1B.x + wa1B.y + wb21, wf2B = wa2B.x + wa2B.y + wb22;

    // ---------------- bMLP from LDS (shared reads, A&B) --------------------
    v2f accA[6], accB[6];
    #pragma unroll
    for (int c = 0; c < 6; ++c) {
        const v2f b2v = {bb2[n * 12 + 2 * c], bb2[n * 12 + 2 * c + 1]};
        accA[c] = b2v; accB[c] = b2v;
    }
    #pragma unroll 2
    for (int r = 0; r < 64; ++r) {
        const float4* rp = (const float4*)(lds + 768 + r * 32);
        const float4 q0 = rp[0], q1 = rp[1];
        const float4 e0 = rp[2], e1 = rp[3], e2 = rp[4];
        const float4 o0 = rp[5], o1 = rp[6], o2 = rp[7];
        const v2f w1a = {q0.x, q0.y}, w1b = {q0.z, q0.w}, bb = {q1.x, q1.y};
        const v2f E[6] = {{e0.x, e0.y}, {e0.z, e0.w}, {e1.x, e1.y}, {e1.z, e1.w}, {e2.x, e2.y}, {e2.z, e2.w}};
        const v2f O[6] = {{o0.x, o0.y}, {o0.z, o0.w}, {o1.x, o1.y}, {o1.z, o1.w}, {o2.x, o2.y}, {o2.z, o2.w}};
        const v2f hA = pkmax(pkfma(vx1A, w1b, pkfma(vx0A, w1a, bb)), vz);
        const v2f hB = pkmax(pkfma(vx1B, w1b, pkfma(vx0B, w1a, bb)), vz);
        const v2f hAx = {hA.x, hA.x}, hAy = {hA.y, hA.y};
        const v2f hBx = {hB.x, hB.x}, hBy = {hB.y, hB.y};
        #pragma unroll
        for (int c = 0; c < 6; ++c) {
            accA[c] = pkfma(hAx, E[c], accA[c]);
            accA[c] = pkfma(hAy, O[c], accA[c]);
            accB[c] = pkfma(hBx, E[c], accB[c]);
            accB[c] = pkfma(hBy, O[c], accB[c]);
        }
    }

    // ---------------- epilogue (per point) ---------------------------------
    finish_point(xA.x, xA.y, kf0A, kf1A, kf2A, wf0A, wf1A, wf2A, accA, n, pA,
                 kW1, kb1, kW2, kb2, wW1, wb1, wW2, wb2, out);
    finish_point(xB.x, xB.y, kf0B, kf1B, kf2B, wf0B, wf1B, wf2B, accB, n, pB,
                 kW1, kb1, kW2, kb2, wW1, wb1, wW2, wb2, out);
}

extern "C" void kernel_launch(void* const* d_in, const int* in_sizes, int n_in,
                              void* d_out, int out_size, void* d_ws, size_t ws_size,
                              hipStream_t stream) {
    (void)in_sizes; (void)n_in; (void)d_ws; (void)ws_size; (void)out_size;
    dim3 grid(NBATCH / 512, NJOINT);           // 2 points per thread
    mdn_fused<<<grid, 256, 0, stream>>>(
        (const float*)d_in[0],
        (const float*)d_in[1], (const float*)d_in[2],
        (const float*)d_in[3], (const float*)d_in[4],
        (const float*)d_in[5], (const float*)d_in[6],
        (const float*)d_in[7], (const float*)d_in[8],
        (const float*)d_in[9], (const float*)d_in[10],
        (const float*)d_in[11], (const float*)d_in[12],
        (float*)d_out);
}

// Round 4
// 179.694 us; speedup vs baseline: 1.0055x; 1.0055x over previous
//
#include <hip/hip_runtime.h>
#include <cmath>

// Problem constants: B=32768, N=17, D=2, K=3, H=64 (bMLP hidden=128, out=12)
#define NBATCH 32768
#define NJOINT 17
#define OUT0_ELEMS (NBATCH * NJOINT * 15)          // out[B,N,3,5]
#define KJS_OFF    OUT0_ELEMS                      // k_js[B,N]
#define MASK_OFF   (KJS_OFF + NBATCH * NJOINT)     // mask[B,N,3]

__device__ __forceinline__ float sel3f(int i, float a, float b, float c) {
    return (i == 0) ? a : ((i == 1) ? b : c);
}

// Cold path: exact fp64 recompute of a 2->64->3 MLP (uniform s_load weights).
// Taken only when fp32 logits have a near-tie (< 1e-4 rel) that could flip
// the discrete argmax / argsort decisions. Measured trigger ~0.1% of lanes.
__device__ __noinline__ void mlp64_small(
    const float* __restrict__ W1a, const float* __restrict__ W1b,
    const float* __restrict__ b1,  const float* __restrict__ W2,
    const float* __restrict__ b2,
    double x0, double x1, double& l0, double& l1, double& l2)
{
    l0 = (double)b2[0]; l1 = (double)b2[1]; l2 = (double)b2[2];
    for (int h = 0; h < 64; ++h) {
        double hv = fma(x1, (double)W1b[h], fma(x0, (double)W1a[h], (double)b1[h]));
        hv = fmax(hv, 0.0);
        l0 = fma(hv, (double)W2[h * 3 + 0], l0);
        l1 = fma(hv, (double)W2[h * 3 + 1], l1);
        l2 = fma(hv, (double)W2[h * 3 + 2], l2);
    }
}

// R1 structure (best measured: VALU 51%), fp32-ized + k/w loops merged so each
// s_load wait window covers 2x the FMA work. Weights stay wave-uniform
// (n = blockIdx.y) -> pure s_load traffic, sK$-resident after first wave.
__global__ __launch_bounds__(256) void mdn_fused(
    const float* __restrict__ pred_pts,
    const float* __restrict__ kW1, const float* __restrict__ kb1,
    const float* __restrict__ kW2, const float* __restrict__ kb2,
    const float* __restrict__ wW1, const float* __restrict__ wb1,
    const float* __restrict__ wW2, const float* __restrict__ wb2,
    const float* __restrict__ bW1, const float* __restrict__ bb1,
    const float* __restrict__ bW2, const float* __restrict__ bb2,
    float* __restrict__ out)
{
    const int n = blockIdx.y;
    const int b = blockIdx.x * 256 + threadIdx.x;
    const int p = b * NJOINT + n;

    const float2 xv = *reinterpret_cast<const float2*>(pred_pts + 2 * p);
    const float x0f = xv.x, x1f = xv.y;

    // -------- merged kMLP + wMLP : 2 -> 64 -> 3 each, fp32 scalar ----------
    const float* kW1a = kW1 + n * 128;
    const float* kW1b = kW1a + 64;
    const float* kb1p = kb1 + n * 64;
    const float* kW2p = kW2 + n * 192;
    const float* wW1a = wW1 + n * 128;
    const float* wW1b = wW1a + 64;
    const float* wb1p = wb1 + n * 64;
    const float* wW2p = wW2 + n * 192;

    float kf0 = kb2[n * 3 + 0], kf1 = kb2[n * 3 + 1], kf2 = kb2[n * 3 + 2];
    float wf0 = wb2[n * 3 + 0], wf1 = wb2[n * 3 + 1], wf2 = wb2[n * 3 + 2];
    #pragma unroll 8
    for (int h = 0; h < 64; ++h) {
        const float khv = fmaxf(fmaf(x1f, kW1b[h], fmaf(x0f, kW1a[h], kb1p[h])), 0.0f);
        kf0 = fmaf(khv, kW2p[h * 3 + 0], kf0);
        kf1 = fmaf(khv, kW2p[h * 3 + 1], kf1);
        kf2 = fmaf(khv, kW2p[h * 3 + 2], kf2);
        const float whv = fmaxf(fmaf(x1f, wW1b[h], fmaf(x0f, wW1a[h], wb1p[h])), 0.0f);
        wf0 = fmaf(whv, wW2p[h * 3 + 0], wf0);
        wf1 = fmaf(whv, wW2p[h * 3 + 1], wf1);
        wf2 = fmaf(whv, wW2p[h * 3 + 2], wf2);
    }

    // k argmax with fp64 fallback on near-tie
    double kl0 = (double)kf0, kl1 = (double)kf1, kl2 = (double)kf2;
    {
        const float d01 = fabsf(kf0 - kf1), d02 = fabsf(kf0 - kf2), d12 = fabsf(kf1 - kf2);
        const float sc = fmaxf(fmaxf(fabsf(kf0), fabsf(kf1)), fabsf(kf2));
        if (fminf(fminf(d01, d02), d12) < 1e-4f * fmaxf(sc, 1.0f))
            mlp64_small(kW1a, kW1b, kb1p, kW2p, kb2 + n * 3,
                        (double)x0f, (double)x1f, kl0, kl1, kl2);
    }
    int kj = 0;  // first-occurrence argmax (jnp.argmax semantics)
    {
        double m = kl0;
        if (kl1 > m) { m = kl1; kj = 1; }
        if (kl2 > m) { kj = 2; }
    }

    // w argsort with fp64 fallback on near-tie
    double wl0 = (double)wf0, wl1 = (double)wf1, wl2 = (double)wf2;
    {
        const float d01 = fabsf(wf0 - wf1), d02 = fabsf(wf0 - wf2), d12 = fabsf(wf1 - wf2);
        const float sc = fmaxf(fmaxf(fabsf(wf0), fabsf(wf1)), fabsf(wf2));
        if (fminf(fminf(d01, d02), d12) < 1e-4f * fmaxf(sc, 1.0f))
            mlp64_small(wW1a, wW1b, wb1p, wW2p, wb2 + n * 3,
                        (double)x0f, (double)x1f, wl0, wl1, wl2);
    }
    // stable descending argsort of 3 (jnp.argsort(-w): ties -> lower index first)
    int i0 = 0;
    {
        double m = wl0;
        if (wl1 > m) { m = wl1; i0 = 1; }
        if (wl2 > m) { i0 = 2; }
    }
    const int ia = (i0 == 0) ? 1 : 0;
    const int ib = (i0 == 2) ? 1 : 2;
    const double wa = ia ? wl1 : wl0;
    const double wb = (ib == 1) ? wl1 : wl2;
    const int i1 = (wb > wa) ? ib : ia;
    const int i2 = (wb > wa) ? ia : ib;

    // softmax from fp32 logits (2% tolerance; fp32 error ~1e-6)
    const float mw = fmaxf(fmaxf(wf0, wf1), wf2);
    const float e0 = __expf(wf0 - mw);
    const float e1 = __expf(wf1 - mw);
    const float e2 = __expf(wf2 - mw);
    const float inv = 1.0f / (e0 + e1 + e2);
    const float p0 = e0 * inv, p1 = e1 * inv, p2 = e2 * inv;

    // ---------------- bMLP : 2 -> 128 -> 12, fp32 scalar (R1 pattern) ------
    float acc[12];
    {
        const float* W1a = bW1 + n * 256;
        const float* W1b = W1a + 128;
        const float* b1  = bb1 + n * 128;
        const float* W2  = bW2 + n * 1536;
        const float* b2  = bb2 + n * 12;
        #pragma unroll
        for (int j = 0; j < 12; ++j) acc[j] = b2[j];
        #pragma unroll 4
        for (int h = 0; h < 128; ++h) {
            const float hv = fmaxf(fmaf(x1f, W1b[h], fmaf(x0f, W1a[h], b1[h])), 0.0f);
            #pragma unroll
            for (int j = 0; j < 12; ++j)
                acc[j] = fmaf(hv, W2[h * 12 + j], acc[j]);
        }
    }

    // ---------------- epilogue: gather by sort order, write ----------------
    float r[15];
    r[0]  = p0; r[5] = p1; r[10] = p2;
    r[1]  = sel3f(i0, acc[0], acc[4], acc[8]);
    r[2]  = sel3f(i0, acc[1], acc[5], acc[9]);
    r[3]  = __expf(sel3f(i0, acc[2], acc[6], acc[10]));
    r[4]  = __expf(sel3f(i0, acc[3], acc[7], acc[11]));
    r[6]  = sel3f(i1, acc[0], acc[4], acc[8]);
    r[7]  = sel3f(i1, acc[1], acc[5], acc[9]);
    r[8]  = __expf(sel3f(i1, acc[2], acc[6], acc[10]));
    r[9]  = __expf(sel3f(i1, acc[3], acc[7], acc[11]));
    r[11] = sel3f(i2, acc[0], acc[4], acc[8]);
    r[12] = sel3f(i2, acc[1], acc[5], acc[9]);
    r[13] = __expf(sel3f(i2, acc[2], acc[6], acc[10]));
    r[14] = __expf(sel3f(i2, acc[3], acc[7], acc[11]));

    float* o = out + (size_t)p * 15;
    #pragma unroll
    for (int i = 0; i < 15; ++i) o[i] = r[i];

    out[KJS_OFF + p] = (float)(kj + 1);

    float* mk = out + MASK_OFF + (size_t)p * 3;
    mk[0] = 1.0f;
    mk[1] = (kj >= 1) ? 1.0f : 0.0f;
    mk[2] = (kj >= 2) ? 1.0f : 0.0f;
}

extern "C" void kernel_launch(void* const* d_in, const int* in_sizes, int n_in,
                              void* d_out, int out_size, void* d_ws, size_t ws_size,
                              hipStream_t stream) {
    (void)in_sizes; (void)n_in; (void)d_ws; (void)ws_size; (void)out_size;
    dim3 grid(NBATCH / 256, NJOINT);
    mdn_fused<<<grid, 256, 0, stream>>>(
        (const float*)d_in[0],
        (const float*)d_in[1], (const float*)d_in[2],
        (const float*)d_in[3], (const float*)d_in[4],
        (const float*)d_in[5], (const float*)d_in[6],
        (const float*)d_in[7], (const float*)d_in[8],
        (const float*)d_in[9], (const float*)d_in[10],
        (const float*)d_in[11], (const float*)d_in[12],
        (float*)d_out);
}